// Round 3
// baseline (159.985 us; speedup 1.0000x reference)
//
#include <hip/hip_runtime.h>

#define NEG_SLOPE 0.2f
#define NXCD 8

// Algebraic collapse: out = mean_n(GATConv) = (1/N) * (sum_e alpha_e * x[src_e]) @ W + bias
//   with per-node logits a_s = x@(W@att_src), a_d = x@(W@att_dst).
// h = x@W never materialized; softmax max-subtraction dropped (logits ~N(0,4),
// exp(e) <= ~1e4, no fp32 overflow; alpha mathematically identical).
//
// Edge-pass atomics: device-scope atomicAdd on gfx950 executes memory-side
// (round-2 profile: 25 MB HBM WRITE for 3.4 MB of atomic data, ~17 atomics/ns
// chip-wide cap). Instead keep NXCD per-XCD copies and use WORKGROUP-scope
// atomics, which execute in the XCD-local L2; the executing XCD id comes from
// s_getreg(HW_REG_XCC_ID) (HW-verified on gfx950). Kernel-boundary release
// writes the dirty L2 lines back before the reduce kernel reads them.

__device__ __forceinline__ int xcd_id() {
    int x;
    asm("s_getreg_b32 %0, hwreg(HW_REG_XCC_ID)" : "=s"(x));
    return x & (NXCD - 1);
}

__device__ __forceinline__ void atomic_add_l2(float* p, float v) {
    __hip_atomic_fetch_add(p, v, __ATOMIC_RELAXED, __HIP_MEMORY_SCOPE_WORKGROUP);
}

// K-init: zero the per-XCD accumulator copies (denom8 ++ s8, contiguous).
__global__ void k_zero(float4* __restrict__ p, int n4) {
    int i = blockIdx.x * blockDim.x + threadIdx.x;
    if (i < n4) p[i] = make_float4(0.f, 0.f, 0.f, 0.f);
}

// K0: wsv = W @ att_src, wdv = W @ att_dst (tiny), zero t.
__global__ void k_prep(const float* __restrict__ W, const float* __restrict__ att_src,
                       const float* __restrict__ att_dst, float* __restrict__ wsv,
                       float* __restrict__ wdv, float* __restrict__ t) {
    __shared__ float l_as[200], l_ad[200];
    int tid = threadIdx.x;           // block = 512
    if (tid < 200) l_as[tid] = att_src[tid];
    else if (tid < 400) l_ad[tid - 200] = att_dst[tid - 200];
    __syncthreads();
    if (tid < 400) {
        int k = tid >> 2, j = tid & 3;
        const float* row = W + (size_t)k * 200 + j * 50;
        const float* as = l_as + j * 50;
        const float* ad = l_ad + j * 50;
        float s0 = 0.f, s1 = 0.f;
        #pragma unroll
        for (int i = 0; i < 50; ++i) {
            float w = row[i];
            s0 = fmaf(w, as[i], s0);
            s1 = fmaf(w, ad[i], s1);
        }
        s0 += __shfl_xor(s0, 1); s0 += __shfl_xor(s0, 2);
        s1 += __shfl_xor(s1, 1); s1 += __shfl_xor(s1, 2);
        if (j == 0) { wsv[k] = s0; wdv[k] = s1; t[k] = 0.f; }
    }
}

// K1: a_s[n] = x[n]·wsv, a_d[n] = x[n]·wdv.
// Coalesced quad layout: thread owns quad q of row r; 250 consecutive threads
// read 10 rows = 4000B contiguous. One block = 10 rows.
__global__ void k_node(const float* __restrict__ x, const float* __restrict__ wsv,
                       const float* __restrict__ wdv, float* __restrict__ a_s,
                       float* __restrict__ a_d, int N) {
    __shared__ float lws[100], lwd[100];
    __shared__ float p0[256], p1[256];
    int tid = threadIdx.x;           // block = 256, 250 active
    if (tid < 100) { lws[tid] = wsv[tid]; lwd[tid] = wdv[tid]; }
    __syncthreads();
    int r = tid / 25, q = tid - r * 25;
    int row = blockIdx.x * 10 + r;
    float s0 = 0.f, s1 = 0.f;
    if (tid < 250 && row < N) {
        float4 v = *reinterpret_cast<const float4*>(x + (size_t)row * 100 + q * 4);
        const float* ws = lws + q * 4;
        const float* wd = lwd + q * 4;
        s0 = v.x * ws[0] + v.y * ws[1] + v.z * ws[2] + v.w * ws[3];
        s1 = v.x * wd[0] + v.y * wd[1] + v.z * wd[2] + v.w * wd[3];
    }
    p0[tid] = s0;
    p1[tid] = s1;
    __syncthreads();
    if (tid < 20) {
        int rr = tid >> 1;
        int row2 = blockIdx.x * 10 + rr;
        if (row2 < N) {
            const float* p = (tid & 1) ? p1 : p0;
            float acc = 0.f;
            #pragma unroll
            for (int j = 0; j < 25; ++j) acc += p[rr * 25 + j];
            if (tid & 1) a_d[row2] = acc;
            else         a_s[row2] = acc;
        }
    }
}

__device__ __forceinline__ float edge_logit(const int* __restrict__ ei,
                                            const float* __restrict__ a_s,
                                            const float* __restrict__ a_d,
                                            int i, int E, int& src, int& dst) {
    if (i < E) { src = ei[i]; dst = ei[E + i]; }
    else       { src = dst = i - E; }   // self loops appended
    float e = a_s[src] + a_d[dst];
    return (e >= 0.f) ? e : NEG_SLOPE * e;
}

// K2: denom8[xcd][dst] += exp(e), XCD-local L2 atomics.
__global__ void k_edge_denom(const int* __restrict__ ei, const float* __restrict__ a_s,
                             const float* __restrict__ a_d, float* __restrict__ denom8,
                             int E, int N, int NP) {
    int i = blockIdx.x * blockDim.x + threadIdx.x;
    if (i >= E + N) return;
    int src, dst;
    float e = edge_logit(ei, a_s, a_d, i, E, src, dst);
    atomic_add_l2(denom8 + (size_t)xcd_id() * NP + dst, __expf(e));
}

// K-reduce: dst[n] = sum_c src8[c][n].
__global__ void k_reduce8(const float* __restrict__ src8, float* __restrict__ dst,
                          int N, int NP) {
    int n = blockIdx.x * blockDim.x + threadIdx.x;
    if (n >= N) return;
    float s = 0.f;
    #pragma unroll
    for (int c = 0; c < NXCD; ++c) s += src8[(size_t)c * NP + n];
    dst[n] = s;
}

// K3: alpha = exp(e)/denom[dst]; s8[xcd][src] += alpha, XCD-local L2 atomics.
__global__ void k_edge_scatter(const int* __restrict__ ei, const float* __restrict__ a_s,
                               const float* __restrict__ a_d, const float* __restrict__ denom,
                               float* __restrict__ s8, int E, int N, int NP) {
    int i = blockIdx.x * blockDim.x + threadIdx.x;
    if (i >= E + N) return;
    int src, dst;
    float e = edge_logit(ei, a_s, a_d, i, E, src, dst);
    float alpha = __expf(e) / denom[dst];
    atomic_add_l2(s8 + (size_t)xcd_id() * NP + src, alpha);
}

// K4: t[k] = sum_n s[n] * x[n,k]. Coalesced quad layout, grid-strided,
// block-level LDS reduction, 100 device-scope atomics per block.
__global__ void k_colsum(const float* __restrict__ x, const float* __restrict__ s_src,
                         float* __restrict__ t, int N) {
    __shared__ float4 lacc[512];
    int tid = threadIdx.x;           // block = 512, 500 active (20 rows/iter)
    int r = tid / 25, q = tid - r * 25;
    float4 acc = make_float4(0.f, 0.f, 0.f, 0.f);
    if (tid < 500) {
        for (int n0 = blockIdx.x * 20; n0 < N; n0 += gridDim.x * 20) {
            int row = n0 + r;
            if (row < N) {
                float w = s_src[row];
                float4 v = *reinterpret_cast<const float4*>(x + (size_t)row * 100 + q * 4);
                acc.x = fmaf(w, v.x, acc.x);
                acc.y = fmaf(w, v.y, acc.y);
                acc.z = fmaf(w, v.z, acc.z);
                acc.w = fmaf(w, v.w, acc.w);
            }
        }
    }
    lacc[tid] = acc;
    __syncthreads();
    if (tid < 25) {
        float4 a = lacc[tid];
        #pragma unroll
        for (int rr = 1; rr < 20; ++rr) {
            float4 b = lacc[rr * 25 + tid];
            a.x += b.x; a.y += b.y; a.z += b.z; a.w += b.w;
        }
        atomicAdd(t + 4 * tid + 0, a.x);
        atomicAdd(t + 4 * tid + 1, a.y);
        atomicAdd(t + 4 * tid + 2, a.z);
        atomicAdd(t + 4 * tid + 3, a.w);
    }
}

// K5: out[f] = (t @ W)[f] / N + bias[f].  Coalesced over f.
__global__ void k_final(const float* __restrict__ t, const float* __restrict__ W,
                        const float* __restrict__ bias, float* __restrict__ out,
                        int N, int F_in, int F_out) {
    int f = blockIdx.x * blockDim.x + threadIdx.x;
    if (f >= F_out) return;
    float acc = 0.f;
    for (int k = 0; k < F_in; ++k) {
        acc = fmaf(t[k], W[(size_t)k * F_out + f], acc);
    }
    out[f] = acc / (float)N + bias[f];
}

extern "C" void kernel_launch(void* const* d_in, const int* in_sizes, int n_in,
                              void* d_out, int out_size, void* d_ws, size_t ws_size,
                              hipStream_t stream) {
    const float* x       = (const float*)d_in[0];
    const int*   ei      = (const int*)d_in[1];
    const float* W       = (const float*)d_in[2];
    const float* att_src = (const float*)d_in[3];
    const float* att_dst = (const float*)d_in[4];
    const float* bias    = (const float*)d_in[5];
    float* out = (float*)d_out;

    const int F_out = in_sizes[3];             // 200
    const int F_in  = in_sizes[2] / F_out;     // 100
    const int N     = in_sizes[0] / F_in;      // 50000
    const int E     = in_sizes[1] / 2;         // 800000
    const int T     = E + N;
    const int NP    = (N + 63) & ~63;          // per-copy stride, 64-float aligned

    float* ws = (float*)d_ws;
    float* wsv    = ws;            // [128]
    float* wdv    = ws + 128;      // [128]
    float* t      = ws + 256;      // [128]
    float* a_s    = ws + 384;      // [N]
    float* a_d    = a_s + N;       // [N]
    float* denom  = a_d + N;       // [N]
    float* s_src  = denom + N;     // [N]
    float* denom8 = s_src + N;     // [NXCD*NP]
    float* s8     = denom8 + (size_t)NXCD * NP;  // [NXCD*NP]

    {   // zero denom8 ++ s8 (contiguous)
        int n4 = 2 * NXCD * NP / 4;
        k_zero<<<(n4 + 255) / 256, 256, 0, stream>>>((float4*)denom8, n4);
    }
    k_prep<<<1, 512, 0, stream>>>(W, att_src, att_dst, wsv, wdv, t);

    k_node<<<(N + 9) / 10, 256, 0, stream>>>(x, wsv, wdv, a_s, a_d, N);

    {
        int blk = 256;
        int grid = (T + blk - 1) / blk;
        k_edge_denom<<<grid, blk, 0, stream>>>(ei, a_s, a_d, denom8, E, N, NP);
        k_reduce8<<<(N + 255) / 256, 256, 0, stream>>>(denom8, denom, N, NP);
        k_edge_scatter<<<grid, blk, 0, stream>>>(ei, a_s, a_d, denom, s8, E, N, NP);
        k_reduce8<<<(N + 255) / 256, 256, 0, stream>>>(s8, s_src, N, NP);
    }

    k_colsum<<<256, 512, 0, stream>>>(x, s_src, t, N);

    k_final<<<(F_out + 255) / 256, 256, 0, stream>>>(t, W, bias, out, N, F_in, F_out);
}

// Round 4
// 147.251 us; speedup vs baseline: 1.0865x; 1.0865x over previous
//
#include <hip/hip_runtime.h>

#define NEG_SLOPE 0.2f
#define NBLK 256        // hist/scatter blocks
#define RSH  6          // nodes per bin = 64
#define RBIN 64
#define CAP  1280       // record slots per bin (mean T/B=1087, sigma~33 -> +6 sigma)
#define MAXB 1024       // max bins supported by LDS arrays (N <= 65536)

typedef unsigned int uint;

// Algebra: out = mean_n(GATConv) = (1/N) * (sum_e alpha_e * x[src_e]) @ W + bias,
// per-node logits a_s = x@(W@att_src), a_d = x@(W@att_dst). h=x@W never built;
// softmax max-subtraction dropped (logits ~N(0,4), exp<=~2e4, fp32 safe).
//
// Round-3 lesson: fp32 global atomics on gfx950 execute memory-side (Infinity
// Cache) regardless of scope -> 850K scattered RMWs = ~45us/pass. So the two
// segment-sums are done via counting-sort into per-bin records (plain stores,
// LDS cursors) + per-bin LDS accumulation. Zero device atomics on the edge path.

// ---------------- shared small kernels ----------------

// K0: wsv = W @ att_src, wdv = W @ att_dst ; zero t.
__global__ void k_prep(const float* __restrict__ W, const float* __restrict__ att_src,
                       const float* __restrict__ att_dst, float* __restrict__ wsv,
                       float* __restrict__ wdv, float* __restrict__ t) {
    __shared__ float l_as[200], l_ad[200];
    int tid = threadIdx.x;           // block = 512
    if (tid < 200) l_as[tid] = att_src[tid];
    else if (tid < 400) l_ad[tid - 200] = att_dst[tid - 200];
    __syncthreads();
    if (tid < 400) {
        int k = tid >> 2, j = tid & 3;
        const float* row = W + (size_t)k * 200 + j * 50;
        const float* as = l_as + j * 50;
        const float* ad = l_ad + j * 50;
        float s0 = 0.f, s1 = 0.f;
        #pragma unroll
        for (int i = 0; i < 50; ++i) {
            float w = row[i];
            s0 = fmaf(w, as[i], s0);
            s1 = fmaf(w, ad[i], s1);
        }
        s0 += __shfl_xor(s0, 1); s0 += __shfl_xor(s0, 2);
        s1 += __shfl_xor(s1, 1); s1 += __shfl_xor(s1, 2);
        if (j == 0) { wsv[k] = s0; wdv[k] = s1; t[k] = 0.f; }
    }
}

// K1: a_s[n] = x[n]·wsv, a_d[n] = x[n]·wdv. Coalesced quad layout (10 rows/block).
__global__ void k_node(const float* __restrict__ x, const float* __restrict__ wsv,
                       const float* __restrict__ wdv, float* __restrict__ a_s,
                       float* __restrict__ a_d, int N) {
    __shared__ float lws[100], lwd[100];
    __shared__ float p0[256], p1[256];
    int tid = threadIdx.x;           // block = 256, 250 active
    if (tid < 100) { lws[tid] = wsv[tid]; lwd[tid] = wdv[tid]; }
    __syncthreads();
    int r = tid / 25, q = tid - r * 25;
    int row = blockIdx.x * 10 + r;
    float s0 = 0.f, s1 = 0.f;
    if (tid < 250 && row < N) {
        float4 v = *reinterpret_cast<const float4*>(x + (size_t)row * 100 + q * 4);
        const float* ws = lws + q * 4;
        const float* wd = lwd + q * 4;
        s0 = v.x * ws[0] + v.y * ws[1] + v.z * ws[2] + v.w * ws[3];
        s1 = v.x * wd[0] + v.y * wd[1] + v.z * wd[2] + v.w * wd[3];
    }
    p0[tid] = s0;
    p1[tid] = s1;
    __syncthreads();
    if (tid < 20) {
        int rr = tid >> 1;
        int row2 = blockIdx.x * 10 + rr;
        if (row2 < N) {
            const float* p = (tid & 1) ? p1 : p0;
            float acc = 0.f;
            #pragma unroll
            for (int j = 0; j < 25; ++j) acc += p[rr * 25 + j];
            if (tid & 1) a_d[row2] = acc;
            else         a_s[row2] = acc;
        }
    }
}

// ---------------- sort path (no device atomics) ----------------

// K2: per-block LDS histograms over dst-bins (A) and src-bins (B); plain-store flush.
__global__ void k_hist(const int* __restrict__ ei, uint* __restrict__ cntA,
                       uint* __restrict__ cntB, int E, int T, int B, int CH) {
    __shared__ uint hA[MAXB], hB[MAXB];
    int tid = threadIdx.x, blk = blockIdx.x;
    for (int b = tid; b < B; b += 256) { hA[b] = 0u; hB[b] = 0u; }
    __syncthreads();
    int i0 = blk * CH, i1 = min(T, i0 + CH);
    for (int i = i0 + tid; i < i1; i += 256) {
        int src, dst;
        if (i < E) { src = ei[i]; dst = ei[E + i]; }
        else       { src = dst = i - E; }
        atomicAdd(&hA[dst >> RSH], 1u);
        atomicAdd(&hB[src >> RSH], 1u);
    }
    __syncthreads();
    for (int b = tid; b < B; b += 256) {
        cntA[(size_t)blk * B + b] = hA[b];
        cntB[(size_t)blk * B + b] = hB[b];
    }
}

// K3: per (sort,bin): exclusive scan over NBLK block-counts -> per-block offsets
// (in-place overwrite of cnt with b*CAP + exclusive prefix); also bin totals.
__global__ void k_offs(uint* __restrict__ cntA, uint* __restrict__ cntB,
                       uint* __restrict__ totA, uint* __restrict__ totB, int B) {
    __shared__ uint sv[NBLK];
    int tid = threadIdx.x;
    int bi = blockIdx.x;
    int isB = bi >= B;
    int b = isB ? bi - B : bi;
    uint* cnt = isB ? cntB : cntA;
    uint* tot = isB ? totB : totA;
    uint x = cnt[(size_t)tid * B + b];
    sv[tid] = x;
    __syncthreads();
    #pragma unroll
    for (int off = 1; off < NBLK; off <<= 1) {
        uint y = (tid >= off) ? sv[tid - off] : 0u;
        __syncthreads();
        sv[tid] += y;
        __syncthreads();
    }
    uint incl = sv[tid];
    cnt[(size_t)tid * B + b] = (uint)b * CAP + incl - x;
    if (tid == NBLK - 1) tot[b] = incl;
}

// K4: permutation scatter. Each edge writes two packed 4B records via LDS cursors.
// recA (binned by dst): (dst&63)<<16 | src ; recB (binned by src): (src&63)<<16 | dst.
__global__ void k_scatter(const int* __restrict__ ei, const uint* __restrict__ offsA,
                          const uint* __restrict__ offsB, uint* __restrict__ recA,
                          uint* __restrict__ recB, int E, int T, int B, int CH) {
    __shared__ uint curA[MAXB], curB[MAXB];
    int tid = threadIdx.x, blk = blockIdx.x;
    for (int b = tid; b < B; b += 256) {
        curA[b] = offsA[(size_t)blk * B + b];
        curB[b] = offsB[(size_t)blk * B + b];
    }
    __syncthreads();
    int i0 = blk * CH, i1 = min(T, i0 + CH);
    for (int i = i0 + tid; i < i1; i += 256) {
        int src, dst;
        if (i < E) { src = ei[i]; dst = ei[E + i]; }
        else       { src = dst = i - E; }
        uint sA = atomicAdd(&curA[dst >> RSH], 1u);
        recA[sA] = ((uint)(dst & (RBIN - 1)) << 16) | (uint)src;
        uint sB = atomicAdd(&curB[src >> RSH], 1u);
        recB[sB] = ((uint)(src & (RBIN - 1)) << 16) | (uint)dst;
    }
}

// K5: one block per dst-bin: denom[dst] = sum exp(leaky(a_s[src]+a_d[dst])).
// a_d range in LDS; a_s gathered (L2-resident 200KB); LDS float accumulate; plain store.
__global__ void k_denom(const uint* __restrict__ recA, const uint* __restrict__ totA,
                        const float* __restrict__ a_s, const float* __restrict__ a_d,
                        float* __restrict__ denom, int N) {
    __shared__ float lad[RBIN];
    __shared__ float acc[RBIN];
    int tid = threadIdx.x, b = blockIdx.x;
    if (tid < RBIN) {
        int node = b * RBIN + tid;
        lad[tid] = (node < N) ? a_d[node] : 0.f;
        acc[tid] = 0.f;
    }
    __syncthreads();
    uint j0 = (uint)b * CAP, cnt = totA[b];
    for (uint j = tid; j < cnt; j += 256) {
        uint rec = recA[j0 + j];
        int src = rec & 0xFFFF;
        int dl = rec >> 16;
        float e = a_s[src] + lad[dl];
        e = (e >= 0.f) ? e : NEG_SLOPE * e;
        atomicAdd(&acc[dl], __expf(e));
    }
    __syncthreads();
    if (tid < RBIN) {
        int node = b * RBIN + tid;
        if (node < N) denom[node] = acc[tid];
    }
}

// K6: one block per src-bin: s[src] = sum exp(e)/denom[dst].
__global__ void k_alpha(const uint* __restrict__ recB, const uint* __restrict__ totB,
                        const float* __restrict__ a_s, const float* __restrict__ a_d,
                        const float* __restrict__ denom, float* __restrict__ s_src, int N) {
    __shared__ float las[RBIN];
    __shared__ float acc[RBIN];
    int tid = threadIdx.x, b = blockIdx.x;
    if (tid < RBIN) {
        int node = b * RBIN + tid;
        las[tid] = (node < N) ? a_s[node] : 0.f;
        acc[tid] = 0.f;
    }
    __syncthreads();
    uint j0 = (uint)b * CAP, cnt = totB[b];
    for (uint j = tid; j < cnt; j += 256) {
        uint rec = recB[j0 + j];
        int dst = rec & 0xFFFF;
        int sl = rec >> 16;
        float e = las[sl] + a_d[dst];
        e = (e >= 0.f) ? e : NEG_SLOPE * e;
        float alpha = __expf(e) / denom[dst];
        atomicAdd(&acc[sl], alpha);
    }
    __syncthreads();
    if (tid < RBIN) {
        int node = b * RBIN + tid;
        if (node < N) s_src[node] = acc[tid];
    }
}

// ---------------- fallback path (device atomics, proven round 1-3) ----------------

__global__ void k_zero_ds(float* __restrict__ p, int n) {
    int i = blockIdx.x * blockDim.x + threadIdx.x;
    if (i < n) p[i] = 0.f;
}

__device__ __forceinline__ float edge_logit(const int* __restrict__ ei,
                                            const float* __restrict__ a_s,
                                            const float* __restrict__ a_d,
                                            int i, int E, int& src, int& dst) {
    if (i < E) { src = ei[i]; dst = ei[E + i]; }
    else       { src = dst = i - E; }
    float e = a_s[src] + a_d[dst];
    return (e >= 0.f) ? e : NEG_SLOPE * e;
}

__global__ void k_edge_denom_dev(const int* __restrict__ ei, const float* __restrict__ a_s,
                                 const float* __restrict__ a_d, float* __restrict__ denom,
                                 int E, int N) {
    int i = blockIdx.x * blockDim.x + threadIdx.x;
    if (i >= E + N) return;
    int src, dst;
    float e = edge_logit(ei, a_s, a_d, i, E, src, dst);
    atomicAdd(denom + dst, __expf(e));
}

__global__ void k_edge_scatter_dev(const int* __restrict__ ei, const float* __restrict__ a_s,
                                   const float* __restrict__ a_d, const float* __restrict__ denom,
                                   float* __restrict__ s_src, int E, int N) {
    int i = blockIdx.x * blockDim.x + threadIdx.x;
    if (i >= E + N) return;
    int src, dst;
    float e = edge_logit(ei, a_s, a_d, i, E, src, dst);
    float alpha = __expf(e) / denom[dst];
    atomicAdd(s_src + src, alpha);
}

// ---------------- tail ----------------

// K7: t[k] = sum_n s[n] * x[n,k]. Coalesced quads, grid-stride, LDS reduce,
// 100 device atomics per block (negligible count).
__global__ void k_colsum(const float* __restrict__ x, const float* __restrict__ s_src,
                         float* __restrict__ t, int N) {
    __shared__ float4 lacc[512];
    int tid = threadIdx.x;           // block = 512, 500 active (20 rows/iter)
    int r = tid / 25, q = tid - r * 25;
    float4 acc = make_float4(0.f, 0.f, 0.f, 0.f);
    if (tid < 500) {
        for (int n0 = blockIdx.x * 20; n0 < N; n0 += gridDim.x * 20) {
            int row = n0 + r;
            if (row < N) {
                float w = s_src[row];
                float4 v = *reinterpret_cast<const float4*>(x + (size_t)row * 100 + q * 4);
                acc.x = fmaf(w, v.x, acc.x);
                acc.y = fmaf(w, v.y, acc.y);
                acc.z = fmaf(w, v.z, acc.z);
                acc.w = fmaf(w, v.w, acc.w);
            }
        }
    }
    lacc[tid] = acc;
    __syncthreads();
    if (tid < 25) {
        float4 a = lacc[tid];
        #pragma unroll
        for (int rr = 1; rr < 20; ++rr) {
            float4 b = lacc[rr * 25 + tid];
            a.x += b.x; a.y += b.y; a.z += b.z; a.w += b.w;
        }
        atomicAdd(t + 4 * tid + 0, a.x);
        atomicAdd(t + 4 * tid + 1, a.y);
        atomicAdd(t + 4 * tid + 2, a.z);
        atomicAdd(t + 4 * tid + 3, a.w);
    }
}

// K8: out[f] = (t @ W)[f] / N + bias[f].
__global__ void k_final(const float* __restrict__ t, const float* __restrict__ W,
                        const float* __restrict__ bias, float* __restrict__ out,
                        int N, int F_in, int F_out) {
    int f = blockIdx.x * blockDim.x + threadIdx.x;
    if (f >= F_out) return;
    float acc = 0.f;
    for (int k = 0; k < F_in; ++k) {
        acc = fmaf(t[k], W[(size_t)k * F_out + f], acc);
    }
    out[f] = acc / (float)N + bias[f];
}

extern "C" void kernel_launch(void* const* d_in, const int* in_sizes, int n_in,
                              void* d_out, int out_size, void* d_ws, size_t ws_size,
                              hipStream_t stream) {
    const float* x       = (const float*)d_in[0];
    const int*   ei      = (const int*)d_in[1];
    const float* W       = (const float*)d_in[2];
    const float* att_src = (const float*)d_in[3];
    const float* att_dst = (const float*)d_in[4];
    const float* bias    = (const float*)d_in[5];
    float* out = (float*)d_out;

    const int F_out = in_sizes[3];             // 200
    const int F_in  = in_sizes[2] / F_out;     // 100
    const int N     = in_sizes[0] / F_in;      // 50000
    const int E     = in_sizes[1] / 2;         // 800000
    const int T     = E + N;
    const int B     = (N + RBIN - 1) >> RSH;   // 782 bins
    const int CH    = (T + NBLK - 1) / NBLK;   // edges per hist/scatter block

    float* ws = (float*)d_ws;
    float* wsv   = ws;            // [128]
    float* wdv   = ws + 128;      // [128]
    float* t     = ws + 256;      // [128]
    float* a_s   = ws + 384;      // [N]
    float* a_d   = a_s + N;       // [N]
    float* denom = a_d + N;       // [N]
    float* s_src = denom + N;     // [N]
    uint*  cntA  = (uint*)(s_src + N);            // [NBLK*B]
    uint*  cntB  = cntA + (size_t)NBLK * B;       // [NBLK*B]
    uint*  totA  = cntB + (size_t)NBLK * B;       // [B]
    uint*  totB  = totA + B;                      // [B]
    uint*  recA  = totB + B;                      // [B*CAP]
    uint*  recB  = recA + (size_t)B * CAP;        // [B*CAP]

    size_t need_bytes = (size_t)((recB + (size_t)B * CAP) - (uint*)ws) * 4;
    bool sort_ok = (ws_size >= need_bytes) && (B <= MAXB) && (N <= 65536);

    k_prep<<<1, 512, 0, stream>>>(W, att_src, att_dst, wsv, wdv, t);
    k_node<<<(N + 9) / 10, 256, 0, stream>>>(x, wsv, wdv, a_s, a_d, N);

    if (sort_ok) {
        k_hist<<<NBLK, 256, 0, stream>>>(ei, cntA, cntB, E, T, B, CH);
        k_offs<<<2 * B, NBLK, 0, stream>>>(cntA, cntB, totA, totB, B);
        k_scatter<<<NBLK, 256, 0, stream>>>(ei, cntA, cntB, recA, recB, E, T, B, CH);
        k_denom<<<B, 256, 0, stream>>>(recA, totA, a_s, a_d, denom, N);
        k_alpha<<<B, 256, 0, stream>>>(recB, totB, a_s, a_d, denom, s_src, N);
    } else {
        k_zero_ds<<<(2 * N + 255) / 256, 256, 0, stream>>>(denom, 2 * N);
        int grid = (T + 255) / 256;
        k_edge_denom_dev<<<grid, 256, 0, stream>>>(ei, a_s, a_d, denom, E, N);
        k_edge_scatter_dev<<<grid, 256, 0, stream>>>(ei, a_s, a_d, denom, s_src, E, N);
    }

    k_colsum<<<512, 512, 0, stream>>>(x, s_src, t, N);
    k_final<<<(F_out + 255) / 256, 256, 0, stream>>>(t, W, bias, out, N, F_in, F_out);
}

// Round 5
// 104.137 us; speedup vs baseline: 1.5363x; 1.4140x over previous
//
#include <hip/hip_runtime.h>

#define NEG_SLOPE 0.2f
#define NBLK 256        // hist/scatter blocks
#define RSH  6          // nodes per bin = 64
#define RBIN 64
#define CAP  1280       // record slots per bin (mean T/B=1087, sigma~33 -> +6 sigma)
#define MAXB 1024       // max bins supported by LDS arrays (N <= 65536)
#define CSB  256        // colsum stage-1 blocks

typedef unsigned int uint;

// Algebra: out = mean_n(GATConv) = (1/N) * (sum_e alpha_e * x[src_e]) @ W + bias,
// per-node logits a_s = x@(W@att_src), a_d = x@(W@att_dst). h=x@W never built;
// softmax max-subtraction dropped (logits ~N(0,4), exp<=~2e4, fp32 safe).
//
// Atomic lessons on gfx950 (rounds 2-4):
//  - fp32 global atomics execute memory-side regardless of scope; scattered over
//    50K addrs: ~19/ns chip-wide (45us/850K). Same-address: serialize per sector
//    (~1/ns chip-wide) -> round-4 k_colsum's 51K same-address tail atomics pinned
//    it at 53us independent of memory traffic.
//  -> edge path: counting-sort + LDS accumulate (zero device atomics).
//  -> colsum: two-stage reduction with plain stores (zero device atomics).

// ---------------- shared small kernels ----------------

// K0: wsv = W @ att_src, wdv = W @ att_dst.
__global__ void k_prep(const float* __restrict__ W, const float* __restrict__ att_src,
                       const float* __restrict__ att_dst, float* __restrict__ wsv,
                       float* __restrict__ wdv) {
    __shared__ float l_as[200], l_ad[200];
    int tid = threadIdx.x;           // block = 512
    if (tid < 200) l_as[tid] = att_src[tid];
    else if (tid < 400) l_ad[tid - 200] = att_dst[tid - 200];
    __syncthreads();
    if (tid < 400) {
        int k = tid >> 2, j = tid & 3;
        const float* row = W + (size_t)k * 200 + j * 50;
        const float* as = l_as + j * 50;
        const float* ad = l_ad + j * 50;
        float s0 = 0.f, s1 = 0.f;
        #pragma unroll
        for (int i = 0; i < 50; ++i) {
            float w = row[i];
            s0 = fmaf(w, as[i], s0);
            s1 = fmaf(w, ad[i], s1);
        }
        s0 += __shfl_xor(s0, 1); s0 += __shfl_xor(s0, 2);
        s1 += __shfl_xor(s1, 1); s1 += __shfl_xor(s1, 2);
        if (j == 0) { wsv[k] = s0; wdv[k] = s1; }
    }
}

// K1: a_s[n] = x[n]·wsv, a_d[n] = x[n]·wdv. Coalesced quad layout (10 rows/block).
__global__ void k_node(const float* __restrict__ x, const float* __restrict__ wsv,
                       const float* __restrict__ wdv, float* __restrict__ a_s,
                       float* __restrict__ a_d, int N) {
    __shared__ float lws[100], lwd[100];
    __shared__ float p0[256], p1[256];
    int tid = threadIdx.x;           // block = 256, 250 active
    if (tid < 100) { lws[tid] = wsv[tid]; lwd[tid] = wdv[tid]; }
    __syncthreads();
    int r = tid / 25, q = tid - r * 25;
    int row = blockIdx.x * 10 + r;
    float s0 = 0.f, s1 = 0.f;
    if (tid < 250 && row < N) {
        float4 v = *reinterpret_cast<const float4*>(x + (size_t)row * 100 + q * 4);
        const float* ws = lws + q * 4;
        const float* wd = lwd + q * 4;
        s0 = v.x * ws[0] + v.y * ws[1] + v.z * ws[2] + v.w * ws[3];
        s1 = v.x * wd[0] + v.y * wd[1] + v.z * wd[2] + v.w * wd[3];
    }
    p0[tid] = s0;
    p1[tid] = s1;
    __syncthreads();
    if (tid < 20) {
        int rr = tid >> 1;
        int row2 = blockIdx.x * 10 + rr;
        if (row2 < N) {
            const float* p = (tid & 1) ? p1 : p0;
            float acc = 0.f;
            #pragma unroll
            for (int j = 0; j < 25; ++j) acc += p[rr * 25 + j];
            if (tid & 1) a_d[row2] = acc;
            else         a_s[row2] = acc;
        }
    }
}

// ---------------- sort path (no device atomics) ----------------

// K2: per-block LDS histograms over dst-bins (A) and src-bins (B); plain-store flush.
__global__ void k_hist(const int* __restrict__ ei, uint* __restrict__ cntA,
                       uint* __restrict__ cntB, int E, int T, int B, int CH) {
    __shared__ uint hA[MAXB], hB[MAXB];
    int tid = threadIdx.x, blk = blockIdx.x;
    for (int b = tid; b < B; b += 256) { hA[b] = 0u; hB[b] = 0u; }
    __syncthreads();
    int i0 = blk * CH, i1 = min(T, i0 + CH);
    for (int i = i0 + tid; i < i1; i += 256) {
        int src, dst;
        if (i < E) { src = ei[i]; dst = ei[E + i]; }
        else       { src = dst = i - E; }
        atomicAdd(&hA[dst >> RSH], 1u);
        atomicAdd(&hB[src >> RSH], 1u);
    }
    __syncthreads();
    for (int b = tid; b < B; b += 256) {
        cntA[(size_t)blk * B + b] = hA[b];
        cntB[(size_t)blk * B + b] = hB[b];
    }
}

// K3: per (sort,bin): exclusive scan over NBLK block-counts -> per-block offsets
// (in-place overwrite of cnt with b*CAP + exclusive prefix); also bin totals.
__global__ void k_offs(uint* __restrict__ cntA, uint* __restrict__ cntB,
                       uint* __restrict__ totA, uint* __restrict__ totB, int B) {
    __shared__ uint sv[NBLK];
    int tid = threadIdx.x;
    int bi = blockIdx.x;
    int isB = bi >= B;
    int b = isB ? bi - B : bi;
    uint* cnt = isB ? cntB : cntA;
    uint* tot = isB ? totB : totA;
    uint x = cnt[(size_t)tid * B + b];
    sv[tid] = x;
    __syncthreads();
    #pragma unroll
    for (int off = 1; off < NBLK; off <<= 1) {
        uint y = (tid >= off) ? sv[tid - off] : 0u;
        __syncthreads();
        sv[tid] += y;
        __syncthreads();
    }
    uint incl = sv[tid];
    cnt[(size_t)tid * B + b] = (uint)b * CAP + incl - x;
    if (tid == NBLK - 1) tot[b] = incl;
}

// K4: permutation scatter. Each edge writes two packed 4B records via LDS cursors.
// recA (binned by dst): (dst&63)<<16 | src ; recB (binned by src): (src&63)<<16 | dst.
__global__ void k_scatter(const int* __restrict__ ei, const uint* __restrict__ offsA,
                          const uint* __restrict__ offsB, uint* __restrict__ recA,
                          uint* __restrict__ recB, int E, int T, int B, int CH) {
    __shared__ uint curA[MAXB], curB[MAXB];
    int tid = threadIdx.x, blk = blockIdx.x;
    for (int b = tid; b < B; b += 256) {
        curA[b] = offsA[(size_t)blk * B + b];
        curB[b] = offsB[(size_t)blk * B + b];
    }
    __syncthreads();
    int i0 = blk * CH, i1 = min(T, i0 + CH);
    for (int i = i0 + tid; i < i1; i += 256) {
        int src, dst;
        if (i < E) { src = ei[i]; dst = ei[E + i]; }
        else       { src = dst = i - E; }
        uint sA = atomicAdd(&curA[dst >> RSH], 1u);
        recA[sA] = ((uint)(dst & (RBIN - 1)) << 16) | (uint)src;
        uint sB = atomicAdd(&curB[src >> RSH], 1u);
        recB[sB] = ((uint)(src & (RBIN - 1)) << 16) | (uint)dst;
    }
}

// K5: one block per dst-bin: denom[dst] = sum exp(leaky(a_s[src]+a_d[dst])).
__global__ void k_denom(const uint* __restrict__ recA, const uint* __restrict__ totA,
                        const float* __restrict__ a_s, const float* __restrict__ a_d,
                        float* __restrict__ denom, int N) {
    __shared__ float lad[RBIN];
    __shared__ float acc[RBIN];
    int tid = threadIdx.x, b = blockIdx.x;
    if (tid < RBIN) {
        int node = b * RBIN + tid;
        lad[tid] = (node < N) ? a_d[node] : 0.f;
        acc[tid] = 0.f;
    }
    __syncthreads();
    uint j0 = (uint)b * CAP, cnt = totA[b];
    for (uint j = tid; j < cnt; j += 256) {
        uint rec = recA[j0 + j];
        int src = rec & 0xFFFF;
        int dl = rec >> 16;
        float e = a_s[src] + lad[dl];
        e = (e >= 0.f) ? e : NEG_SLOPE * e;
        atomicAdd(&acc[dl], __expf(e));
    }
    __syncthreads();
    if (tid < RBIN) {
        int node = b * RBIN + tid;
        if (node < N) denom[node] = acc[tid];
    }
}

// K6: one block per src-bin: s[src] = sum exp(e)/denom[dst].
__global__ void k_alpha(const uint* __restrict__ recB, const uint* __restrict__ totB,
                        const float* __restrict__ a_s, const float* __restrict__ a_d,
                        const float* __restrict__ denom, float* __restrict__ s_src, int N) {
    __shared__ float las[RBIN];
    __shared__ float acc[RBIN];
    int tid = threadIdx.x, b = blockIdx.x;
    if (tid < RBIN) {
        int node = b * RBIN + tid;
        las[tid] = (node < N) ? a_s[node] : 0.f;
        acc[tid] = 0.f;
    }
    __syncthreads();
    uint j0 = (uint)b * CAP, cnt = totB[b];
    for (uint j = tid; j < cnt; j += 256) {
        uint rec = recB[j0 + j];
        int dst = rec & 0xFFFF;
        int sl = rec >> 16;
        float e = las[sl] + a_d[dst];
        e = (e >= 0.f) ? e : NEG_SLOPE * e;
        float alpha = __expf(e) / denom[dst];
        atomicAdd(&acc[sl], alpha);
    }
    __syncthreads();
    if (tid < RBIN) {
        int node = b * RBIN + tid;
        if (node < N) s_src[node] = acc[tid];
    }
}

// ---------------- fallback edge path (device atomics, proven rounds 1-3) ----------------

__global__ void k_zero_ds(float* __restrict__ p, int n) {
    int i = blockIdx.x * blockDim.x + threadIdx.x;
    if (i < n) p[i] = 0.f;
}

__device__ __forceinline__ float edge_logit(const int* __restrict__ ei,
                                            const float* __restrict__ a_s,
                                            const float* __restrict__ a_d,
                                            int i, int E, int& src, int& dst) {
    if (i < E) { src = ei[i]; dst = ei[E + i]; }
    else       { src = dst = i - E; }
    float e = a_s[src] + a_d[dst];
    return (e >= 0.f) ? e : NEG_SLOPE * e;
}

__global__ void k_edge_denom_dev(const int* __restrict__ ei, const float* __restrict__ a_s,
                                 const float* __restrict__ a_d, float* __restrict__ denom,
                                 int E, int N) {
    int i = blockIdx.x * blockDim.x + threadIdx.x;
    if (i >= E + N) return;
    int src, dst;
    float e = edge_logit(ei, a_s, a_d, i, E, src, dst);
    atomicAdd(denom + dst, __expf(e));
}

__global__ void k_edge_scatter_dev(const int* __restrict__ ei, const float* __restrict__ a_s,
                                   const float* __restrict__ a_d, const float* __restrict__ denom,
                                   float* __restrict__ s_src, int E, int N) {
    int i = blockIdx.x * blockDim.x + threadIdx.x;
    if (i >= E + N) return;
    int src, dst;
    float e = edge_logit(ei, a_s, a_d, i, E, src, dst);
    float alpha = __expf(e) / denom[dst];
    atomicAdd(s_src + src, alpha);
}

// ---------------- tail ----------------

// K7a: stage 1 of t[k] = sum_n s[n]*x[n,k]. Coalesced quads, grid-stride,
// LDS reduce, PLAIN STORE of 100 partials per block (no atomics).
__global__ void k_colsum1(const float* __restrict__ x, const float* __restrict__ s_src,
                          float* __restrict__ part, int N) {
    __shared__ float4 lacc[512];
    int tid = threadIdx.x;           // block = 512, 500 active (20 rows/iter)
    int r = tid / 25, q = tid - r * 25;
    float4 acc = make_float4(0.f, 0.f, 0.f, 0.f);
    if (tid < 500) {
        for (int n0 = blockIdx.x * 20; n0 < N; n0 += gridDim.x * 20) {
            int row = n0 + r;
            if (row < N) {
                float w = s_src[row];
                float4 v = *reinterpret_cast<const float4*>(x + (size_t)row * 100 + q * 4);
                acc.x = fmaf(w, v.x, acc.x);
                acc.y = fmaf(w, v.y, acc.y);
                acc.z = fmaf(w, v.z, acc.z);
                acc.w = fmaf(w, v.w, acc.w);
            }
        }
    }
    lacc[tid] = acc;
    __syncthreads();
    if (tid < 25) {
        float4 a = lacc[tid];
        #pragma unroll
        for (int rr = 1; rr < 20; ++rr) {
            float4 b = lacc[rr * 25 + tid];
            a.x += b.x; a.y += b.y; a.z += b.z; a.w += b.w;
        }
        *reinterpret_cast<float4*>(part + (size_t)blockIdx.x * 128 + tid * 4) = a;
    }
}

// K7b: stage 2: t[k] = sum_b part[b][k]. Tiny (CSB*100 floats, L2-resident).
__global__ void k_colsum2(const float* __restrict__ part, float* __restrict__ t) {
    int k = threadIdx.x;             // block = 128, 100 active
    if (k >= 100) return;
    float s0 = 0.f, s1 = 0.f, s2 = 0.f, s3 = 0.f;
    for (int b = 0; b < CSB; b += 4) {
        s0 += part[(size_t)b * 128 + k];
        s1 += part[(size_t)(b + 1) * 128 + k];
        s2 += part[(size_t)(b + 2) * 128 + k];
        s3 += part[(size_t)(b + 3) * 128 + k];
    }
    t[k] = (s0 + s1) + (s2 + s3);
}

// K8: out[f] = (t @ W)[f] / N + bias[f].
__global__ void k_final(const float* __restrict__ t, const float* __restrict__ W,
                        const float* __restrict__ bias, float* __restrict__ out,
                        int N, int F_in, int F_out) {
    int f = blockIdx.x * blockDim.x + threadIdx.x;
    if (f >= F_out) return;
    float acc = 0.f;
    for (int k = 0; k < F_in; ++k) {
        acc = fmaf(t[k], W[(size_t)k * F_out + f], acc);
    }
    out[f] = acc / (float)N + bias[f];
}

extern "C" void kernel_launch(void* const* d_in, const int* in_sizes, int n_in,
                              void* d_out, int out_size, void* d_ws, size_t ws_size,
                              hipStream_t stream) {
    const float* x       = (const float*)d_in[0];
    const int*   ei      = (const int*)d_in[1];
    const float* W       = (const float*)d_in[2];
    const float* att_src = (const float*)d_in[3];
    const float* att_dst = (const float*)d_in[4];
    const float* bias    = (const float*)d_in[5];
    float* out = (float*)d_out;

    const int F_out = in_sizes[3];             // 200
    const int F_in  = in_sizes[2] / F_out;     // 100
    const int N     = in_sizes[0] / F_in;      // 50000
    const int E     = in_sizes[1] / 2;         // 800000
    const int T     = E + N;
    const int B     = (N + RBIN - 1) >> RSH;   // 782 bins
    const int CH    = (T + NBLK - 1) / NBLK;   // edges per hist/scatter block

    float* ws = (float*)d_ws;
    float* wsv   = ws;            // [128]
    float* wdv   = ws + 128;      // [128]
    float* t     = ws + 256;      // [128]
    float* a_s   = ws + 384;      // [N]
    float* a_d   = a_s + N;       // [N]
    float* denom = a_d + N;       // [N]
    float* s_src = denom + N;     // [N]
    uint*  cntA  = (uint*)(s_src + N);            // [NBLK*B]  (dead after k_scatter)
    uint*  cntB  = cntA + (size_t)NBLK * B;       // [NBLK*B]
    uint*  totA  = cntB + (size_t)NBLK * B;       // [B]
    uint*  totB  = totA + B;                      // [B]
    uint*  recA  = totB + B;                      // [B*CAP]
    uint*  recB  = recA + (size_t)B * CAP;        // [B*CAP]
    float* part  = (float*)cntA;                  // [CSB*128] aliases dead cntA

    size_t need_bytes = (size_t)((recB + (size_t)B * CAP) - (uint*)ws) * 4;
    bool sort_ok = (ws_size >= need_bytes) && (B <= MAXB) && (N <= 65536);

    k_prep<<<1, 512, 0, stream>>>(W, att_src, att_dst, wsv, wdv);
    k_node<<<(N + 9) / 10, 256, 0, stream>>>(x, wsv, wdv, a_s, a_d, N);

    if (sort_ok) {
        k_hist<<<NBLK, 256, 0, stream>>>(ei, cntA, cntB, E, T, B, CH);
        k_offs<<<2 * B, NBLK, 0, stream>>>(cntA, cntB, totA, totB, B);
        k_scatter<<<NBLK, 256, 0, stream>>>(ei, cntA, cntB, recA, recB, E, T, B, CH);
        k_denom<<<B, 256, 0, stream>>>(recA, totA, a_s, a_d, denom, N);
        k_alpha<<<B, 256, 0, stream>>>(recB, totB, a_s, a_d, denom, s_src, N);
    } else {
        k_zero_ds<<<(2 * N + 255) / 256, 256, 0, stream>>>(denom, 2 * N);
        int grid = (T + 255) / 256;
        k_edge_denom_dev<<<grid, 256, 0, stream>>>(ei, a_s, a_d, denom, E, N);
        k_edge_scatter_dev<<<grid, 256, 0, stream>>>(ei, a_s, a_d, denom, s_src, E, N);
    }

    k_colsum1<<<CSB, 512, 0, stream>>>(x, s_src, part, N);
    k_colsum2<<<1, 128, 0, stream>>>(part, t);
    k_final<<<(F_out + 255) / 256, 256, 0, stream>>>(t, W, bias, out, N, F_in, F_out);
}

// Round 6
// 77.474 us; speedup vs baseline: 2.0650x; 1.3441x over previous
//
#include <hip/hip_runtime.h>

#define NEG_SLOPE 0.2f
#define NBLK 256        // hist/scatter blocks
#define RSH  6          // nodes per bin = 64
#define RBIN 64
#define CAP  1536       // record slots per bin (self 64 + edge mean 1023, sigma~32)
#define MAXB 1024       // max bins supported by LDS arrays (N <= 65536)
#define CSB  256        // colsum stage-1 blocks

typedef unsigned int uint;

// Algebra: out = mean_n(GATConv) = (1/N) * (sum_e alpha_e * x[src_e]) @ W + bias,
// per-node logits a_s = x@(W@att_src), a_d = x@(W@att_dst). h=x@W never built;
// softmax max-subtraction dropped (logits ~N(0,4), exp<=~2e4, fp32 safe).
//
// gfx950 atomic lessons (rounds 2-5):
//  - fp32 global atomics execute memory-side regardless of scope: scattered
//    ~19/ns chip-wide; same-address ~1/ns. Both edge segment-sums and the
//    colsum tail must avoid device atomics entirely.
//  -> counting-sort into per-bin records (LDS cursors, plain stores) + per-bin
//     LDS accumulate; colsum via two-stage plain-store reduction.
// Round-5 lesson: remaining time is spread across 11 small launches (~2-3us
// gaps each) -> fuse to 7: F1={prep|hist|selfrec}, F2={node|offs}, scatter,
// denom, alpha, colsum1, F3={colsum2+final}. Self-loop records get reserved
// slots at the head of each bin (analytic offsets), so hist/scatter run pure
// int4-vectorized loops over the E real edges.

// ---------------- F1: block0=prep, blocks 1..NBLK=hist, rest=selfrec ----------------
__global__ void k_f1(const float* __restrict__ W, const float* __restrict__ att_src,
                     const float* __restrict__ att_dst, const int* __restrict__ ei,
                     float* __restrict__ wsv, float* __restrict__ wdv,
                     uint* __restrict__ cntA, uint* __restrict__ cntB,
                     uint* __restrict__ recA, uint* __restrict__ recB,
                     int E, int N, int B, int F_out) {
    __shared__ uint hA[MAXB], hB[MAXB];
    __shared__ float l_as[256], l_ad[256];
    int tid = threadIdx.x;           // block = 256
    int blk = blockIdx.x;
    if (blk == 0) {
        // prep: wsv = W @ att_src, wdv = W @ att_dst (F_in=100, F_out=200)
        if (tid < 200) { l_as[tid] = att_src[tid]; l_ad[tid] = att_dst[tid]; }
        __syncthreads();
        if (tid < 200) {
            int k = tid >> 1, j = tid & 1;
            const float* row = W + (size_t)k * F_out + j * 100;
            const float* as = l_as + j * 100;
            const float* ad = l_ad + j * 100;
            float s0 = 0.f, s1 = 0.f;
            #pragma unroll
            for (int i = 0; i < 100; ++i) {
                float w = row[i];
                s0 = fmaf(w, as[i], s0);
                s1 = fmaf(w, ad[i], s1);
            }
            s0 += __shfl_xor(s0, 1);
            s1 += __shfl_xor(s1, 1);
            if (j == 0) { wsv[k] = s0; wdv[k] = s1; }
        }
    } else if (blk <= NBLK) {
        // hist over the E real edges (self loops accounted analytically in offs)
        int hb = blk - 1;
        for (int b = tid; b < B; b += 256) { hA[b] = 0u; hB[b] = 0u; }
        __syncthreads();
        if ((E & 3) == 0) {
            int stride = NBLK * 256 * 4;
            for (int i = (hb * 256 + tid) * 4; i < E; i += stride) {
                int4 s4 = *reinterpret_cast<const int4*>(ei + i);
                int4 d4 = *reinterpret_cast<const int4*>(ei + E + i);
                atomicAdd(&hA[d4.x >> RSH], 1u); atomicAdd(&hB[s4.x >> RSH], 1u);
                atomicAdd(&hA[d4.y >> RSH], 1u); atomicAdd(&hB[s4.y >> RSH], 1u);
                atomicAdd(&hA[d4.z >> RSH], 1u); atomicAdd(&hB[s4.z >> RSH], 1u);
                atomicAdd(&hA[d4.w >> RSH], 1u); atomicAdd(&hB[s4.w >> RSH], 1u);
            }
        } else {
            int stride = NBLK * 256;
            for (int i = hb * 256 + tid; i < E; i += stride) {
                int s = ei[i], d = ei[E + i];
                atomicAdd(&hA[d >> RSH], 1u); atomicAdd(&hB[s >> RSH], 1u);
            }
        }
        __syncthreads();
        for (int b = tid; b < B; b += 256) {
            cntA[(size_t)hb * B + b] = hA[b];
            cntB[(size_t)hb * B + b] = hB[b];
        }
    } else {
        // selfrec: node n's self-loop record at reserved slot bin_base + (n&63)
        int idx = blk - NBLK - 1;
        int n0 = idx * 512;
        int n1 = min(N, n0 + 512);
        for (int n = n0 + tid; n < n1; n += 256) {
            int b = n >> RSH, l = n & (RBIN - 1);
            uint rec = ((uint)l << 16) | (uint)n;
            size_t slot = (size_t)b * CAP + l;
            recA[slot] = rec;
            recB[slot] = rec;
        }
    }
}

// ---------------- F2: blocks<NODEB = node logits; rest = offsets scan ----------------
__global__ void k_f2(const float* __restrict__ x, const float* __restrict__ wsv,
                     const float* __restrict__ wdv, float* __restrict__ a_s,
                     float* __restrict__ a_d, uint* __restrict__ cntA,
                     uint* __restrict__ cntB, uint* __restrict__ totA,
                     uint* __restrict__ totB, int N, int B, int NODEB) {
    __shared__ float lws[100], lwd[100];
    __shared__ float p0[256], p1[256];
    __shared__ uint sv[NBLK];
    int tid = threadIdx.x;           // block = 256
    int blk = blockIdx.x;
    if (blk < NODEB) {
        // node: a_s[n]=x[n]·wsv, a_d[n]=x[n]·wdv; coalesced quads, 10 rows/block
        if (tid < 100) { lws[tid] = wsv[tid]; lwd[tid] = wdv[tid]; }
        __syncthreads();
        int r = tid / 25, q = tid - r * 25;
        int row = blk * 10 + r;
        float s0 = 0.f, s1 = 0.f;
        if (tid < 250 && row < N) {
            float4 v = *reinterpret_cast<const float4*>(x + (size_t)row * 100 + q * 4);
            const float* ws = lws + q * 4;
            const float* wd = lwd + q * 4;
            s0 = v.x * ws[0] + v.y * ws[1] + v.z * ws[2] + v.w * ws[3];
            s1 = v.x * wd[0] + v.y * wd[1] + v.z * wd[2] + v.w * wd[3];
        }
        p0[tid] = s0;
        p1[tid] = s1;
        __syncthreads();
        if (tid < 20) {
            int rr = tid >> 1;
            int row2 = blk * 10 + rr;
            if (row2 < N) {
                const float* p = (tid & 1) ? p1 : p0;
                float acc = 0.f;
                #pragma unroll
                for (int j = 0; j < 25; ++j) acc += p[rr * 25 + j];
                if (tid & 1) a_d[row2] = acc;
                else         a_s[row2] = acc;
            }
        }
    } else {
        // offs: per (sort,bin) exclusive scan over NBLK block-counts; base slot
        // skips the bin's reserved self-loop range.
        int bi = blk - NODEB;
        int isB = bi >= B;
        int b = isB ? bi - B : bi;
        uint* cnt = isB ? cntB : cntA;
        uint* tot = isB ? totB : totA;
        int sc = N - b * RBIN; if (sc > RBIN) sc = RBIN;   // self records in bin
        uint v = cnt[(size_t)tid * B + b];
        sv[tid] = v;
        __syncthreads();
        #pragma unroll
        for (int off = 1; off < NBLK; off <<= 1) {
            uint y = (tid >= off) ? sv[tid - off] : 0u;
            __syncthreads();
            sv[tid] += y;
            __syncthreads();
        }
        uint incl = sv[tid];
        cnt[(size_t)tid * B + b] = (uint)b * CAP + (uint)sc + incl - v;
        if (tid == NBLK - 1) tot[b] = (uint)sc + incl;
    }
}

// K-scatter: permutation via LDS cursors; int4-vectorized edge reads.
// recA (binned by dst): (dst&63)<<16|src ; recB (binned by src): (src&63)<<16|dst.
__global__ void k_scatter(const int* __restrict__ ei, const uint* __restrict__ offsA,
                          const uint* __restrict__ offsB, uint* __restrict__ recA,
                          uint* __restrict__ recB, int E, int B) {
    __shared__ uint curA[MAXB], curB[MAXB];
    int tid = threadIdx.x, blk = blockIdx.x;
    for (int b = tid; b < B; b += 256) {
        curA[b] = offsA[(size_t)blk * B + b];
        curB[b] = offsB[(size_t)blk * B + b];
    }
    __syncthreads();
    if ((E & 3) == 0) {
        int stride = NBLK * 256 * 4;
        for (int i = (blk * 256 + tid) * 4; i < E; i += stride) {
            int4 s4 = *reinterpret_cast<const int4*>(ei + i);
            int4 d4 = *reinterpret_cast<const int4*>(ei + E + i);
            {   uint sA = atomicAdd(&curA[d4.x >> RSH], 1u);
                recA[sA] = ((uint)(d4.x & (RBIN - 1)) << 16) | (uint)s4.x;
                uint sB = atomicAdd(&curB[s4.x >> RSH], 1u);
                recB[sB] = ((uint)(s4.x & (RBIN - 1)) << 16) | (uint)d4.x; }
            {   uint sA = atomicAdd(&curA[d4.y >> RSH], 1u);
                recA[sA] = ((uint)(d4.y & (RBIN - 1)) << 16) | (uint)s4.y;
                uint sB = atomicAdd(&curB[s4.y >> RSH], 1u);
                recB[sB] = ((uint)(s4.y & (RBIN - 1)) << 16) | (uint)d4.y; }
            {   uint sA = atomicAdd(&curA[d4.z >> RSH], 1u);
                recA[sA] = ((uint)(d4.z & (RBIN - 1)) << 16) | (uint)s4.z;
                uint sB = atomicAdd(&curB[s4.z >> RSH], 1u);
                recB[sB] = ((uint)(s4.z & (RBIN - 1)) << 16) | (uint)d4.z; }
            {   uint sA = atomicAdd(&curA[d4.w >> RSH], 1u);
                recA[sA] = ((uint)(d4.w & (RBIN - 1)) << 16) | (uint)s4.w;
                uint sB = atomicAdd(&curB[s4.w >> RSH], 1u);
                recB[sB] = ((uint)(s4.w & (RBIN - 1)) << 16) | (uint)d4.w; }
        }
    } else {
        int stride = NBLK * 256;
        for (int i = blk * 256 + tid; i < E; i += stride) {
            int s = ei[i], d = ei[E + i];
            uint sA = atomicAdd(&curA[d >> RSH], 1u);
            recA[sA] = ((uint)(d & (RBIN - 1)) << 16) | (uint)s;
            uint sB = atomicAdd(&curB[s >> RSH], 1u);
            recB[sB] = ((uint)(s & (RBIN - 1)) << 16) | (uint)d;
        }
    }
}

// K-denom: one block per dst-bin: denom[dst] = sum exp(leaky(a_s[src]+a_d[dst])).
__global__ void k_denom(const uint* __restrict__ recA, const uint* __restrict__ totA,
                        const float* __restrict__ a_s, const float* __restrict__ a_d,
                        float* __restrict__ denom, int N) {
    __shared__ float lad[RBIN];
    __shared__ float acc[RBIN];
    int tid = threadIdx.x, b = blockIdx.x;
    if (tid < RBIN) {
        int node = b * RBIN + tid;
        lad[tid] = (node < N) ? a_d[node] : 0.f;
        acc[tid] = 0.f;
    }
    __syncthreads();
    uint j0 = (uint)b * CAP, cnt = totA[b];
    for (uint j = tid; j < cnt; j += 256) {
        uint rec = recA[j0 + j];
        int src = rec & 0xFFFF;
        int dl = rec >> 16;
        float e = a_s[src] + lad[dl];
        e = (e >= 0.f) ? e : NEG_SLOPE * e;
        atomicAdd(&acc[dl], __expf(e));
    }
    __syncthreads();
    if (tid < RBIN) {
        int node = b * RBIN + tid;
        if (node < N) denom[node] = acc[tid];
    }
}

// K-alpha: one block per src-bin: s[src] = sum exp(e)/denom[dst].
__global__ void k_alpha(const uint* __restrict__ recB, const uint* __restrict__ totB,
                        const float* __restrict__ a_s, const float* __restrict__ a_d,
                        const float* __restrict__ denom, float* __restrict__ s_src, int N) {
    __shared__ float las[RBIN];
    __shared__ float acc[RBIN];
    int tid = threadIdx.x, b = blockIdx.x;
    if (tid < RBIN) {
        int node = b * RBIN + tid;
        las[tid] = (node < N) ? a_s[node] : 0.f;
        acc[tid] = 0.f;
    }
    __syncthreads();
    uint j0 = (uint)b * CAP, cnt = totB[b];
    for (uint j = tid; j < cnt; j += 256) {
        uint rec = recB[j0 + j];
        int dst = rec & 0xFFFF;
        int sl = rec >> 16;
        float e = las[sl] + a_d[dst];
        e = (e >= 0.f) ? e : NEG_SLOPE * e;
        float alpha = __expf(e) / denom[dst];
        atomicAdd(&acc[sl], alpha);
    }
    __syncthreads();
    if (tid < RBIN) {
        int node = b * RBIN + tid;
        if (node < N) s_src[node] = acc[tid];
    }
}

// ---------------- fallback edge path (device atomics, proven rounds 1-3) ----------------

__global__ void k_zero_ds(float* __restrict__ p, int n) {
    int i = blockIdx.x * blockDim.x + threadIdx.x;
    if (i < n) p[i] = 0.f;
}

__device__ __forceinline__ float edge_logit(const int* __restrict__ ei,
                                            const float* __restrict__ a_s,
                                            const float* __restrict__ a_d,
                                            int i, int E, int& src, int& dst) {
    if (i < E) { src = ei[i]; dst = ei[E + i]; }
    else       { src = dst = i - E; }
    float e = a_s[src] + a_d[dst];
    return (e >= 0.f) ? e : NEG_SLOPE * e;
}

__global__ void k_edge_denom_dev(const int* __restrict__ ei, const float* __restrict__ a_s,
                                 const float* __restrict__ a_d, float* __restrict__ denom,
                                 int E, int N) {
    int i = blockIdx.x * blockDim.x + threadIdx.x;
    if (i >= E + N) return;
    int src, dst;
    float e = edge_logit(ei, a_s, a_d, i, E, src, dst);
    atomicAdd(denom + dst, __expf(e));
}

__global__ void k_edge_scatter_dev(const int* __restrict__ ei, const float* __restrict__ a_s,
                                   const float* __restrict__ a_d, const float* __restrict__ denom,
                                   float* __restrict__ s_src, int E, int N) {
    int i = blockIdx.x * blockDim.x + threadIdx.x;
    if (i >= E + N) return;
    int src, dst;
    float e = edge_logit(ei, a_s, a_d, i, E, src, dst);
    float alpha = __expf(e) / denom[dst];
    atomicAdd(s_src + src, alpha);
}

// ---------------- tail ----------------

// colsum stage 1: partial t per block, plain stores (no atomics).
__global__ void k_colsum1(const float* __restrict__ x, const float* __restrict__ s_src,
                          float* __restrict__ part, int N) {
    __shared__ float4 lacc[512];
    int tid = threadIdx.x;           // block = 512, 500 active (20 rows/iter)
    int r = tid / 25, q = tid - r * 25;
    float4 acc = make_float4(0.f, 0.f, 0.f, 0.f);
    if (tid < 500) {
        for (int n0 = blockIdx.x * 20; n0 < N; n0 += gridDim.x * 20) {
            int row = n0 + r;
            if (row < N) {
                float w = s_src[row];
                float4 v = *reinterpret_cast<const float4*>(x + (size_t)row * 100 + q * 4);
                acc.x = fmaf(w, v.x, acc.x);
                acc.y = fmaf(w, v.y, acc.y);
                acc.z = fmaf(w, v.z, acc.z);
                acc.w = fmaf(w, v.w, acc.w);
            }
        }
    }
    lacc[tid] = acc;
    __syncthreads();
    if (tid < 25) {
        float4 a = lacc[tid];
        #pragma unroll
        for (int rr = 1; rr < 20; ++rr) {
            float4 b = lacc[rr * 25 + tid];
            a.x += b.x; a.y += b.y; a.z += b.z; a.w += b.w;
        }
        *reinterpret_cast<float4*>(part + (size_t)blockIdx.x * 128 + tid * 4) = a;
    }
}

// F3: single block: t[k] = sum_b part[b][k] (LDS), then out[f] = (t@W)[f]/N + bias[f].
__global__ void k_f3(const float* __restrict__ part, const float* __restrict__ W,
                     const float* __restrict__ bias, float* __restrict__ out,
                     int N, int F_in, int F_out) {
    __shared__ float lt[128];
    int tid = threadIdx.x;           // block = 256
    for (int k = tid; k < F_in; k += 256) {
        float s0 = 0.f, s1 = 0.f, s2 = 0.f, s3 = 0.f;
        for (int b = 0; b < CSB; b += 4) {
            s0 += part[(size_t)b * 128 + k];
            s1 += part[(size_t)(b + 1) * 128 + k];
            s2 += part[(size_t)(b + 2) * 128 + k];
            s3 += part[(size_t)(b + 3) * 128 + k];
        }
        lt[k] = (s0 + s1) + (s2 + s3);
    }
    __syncthreads();
    float inv = 1.f / (float)N;
    for (int f = tid; f < F_out; f += 256) {
        float acc = 0.f;
        for (int k = 0; k < F_in; ++k) {
            acc = fmaf(lt[k], W[(size_t)k * F_out + f], acc);
        }
        out[f] = acc * inv + bias[f];
    }
}

extern "C" void kernel_launch(void* const* d_in, const int* in_sizes, int n_in,
                              void* d_out, int out_size, void* d_ws, size_t ws_size,
                              hipStream_t stream) {
    const float* x       = (const float*)d_in[0];
    const int*   ei      = (const int*)d_in[1];
    const float* W       = (const float*)d_in[2];
    const float* att_src = (const float*)d_in[3];
    const float* att_dst = (const float*)d_in[4];
    const float* bias    = (const float*)d_in[5];
    float* out = (float*)d_out;

    const int F_out = in_sizes[3];             // 200
    const int F_in  = in_sizes[2] / F_out;     // 100
    const int N     = in_sizes[0] / F_in;      // 50000
    const int E     = in_sizes[1] / 2;         // 800000
    const int B     = (N + RBIN - 1) >> RSH;   // 782 bins
    const int NODEB = (N + 9) / 10;            // node blocks in F2
    const int SRB   = (N + 511) / 512;         // selfrec blocks in F1

    float* ws = (float*)d_ws;
    float* wsv   = ws;            // [128]
    float* wdv   = ws + 128;      // [128]
    float* a_s   = ws + 256;      // [N]
    float* a_d   = a_s + N;       // [N]
    float* denom = a_d + N;       // [N]
    float* s_src = denom + N;     // [N]
    uint*  cntA  = (uint*)(s_src + N);            // [NBLK*B] (dead after scatter)
    uint*  cntB  = cntA + (size_t)NBLK * B;       // [NBLK*B]
    uint*  totA  = cntB + (size_t)NBLK * B;       // [B]
    uint*  totB  = totA + B;                      // [B]
    uint*  recA  = totB + B;                      // [B*CAP]
    uint*  recB  = recA + (size_t)B * CAP;        // [B*CAP]
    float* part  = (float*)cntA;                  // [CSB*128] aliases dead cntA

    size_t need_bytes = (size_t)((recB + (size_t)B * CAP) - (uint*)ws) * 4;
    bool sort_ok = (ws_size >= need_bytes) && (B <= MAXB) && (N <= 65536) &&
                   ((size_t)NBLK * 128 >= (size_t)CSB * 128);

    if (sort_ok) {
        k_f1<<<1 + NBLK + SRB, 256, 0, stream>>>(W, att_src, att_dst, ei, wsv, wdv,
                                                 cntA, cntB, recA, recB, E, N, B, F_out);
        k_f2<<<NODEB + 2 * B, 256, 0, stream>>>(x, wsv, wdv, a_s, a_d,
                                                cntA, cntB, totA, totB, N, B, NODEB);
        k_scatter<<<NBLK, 256, 0, stream>>>(ei, cntA, cntB, recA, recB, E, B);
        k_denom<<<B, 256, 0, stream>>>(recA, totA, a_s, a_d, denom, N);
        k_alpha<<<B, 256, 0, stream>>>(recB, totB, a_s, a_d, denom, s_src, N);
    } else {
        k_f1<<<1, 256, 0, stream>>>(W, att_src, att_dst, ei, wsv, wdv,
                                    cntA, cntB, recA, recB, E, N, B, F_out);  // prep only
        k_f2<<<NODEB, 256, 0, stream>>>(x, wsv, wdv, a_s, a_d,
                                        cntA, cntB, totA, totB, N, B, NODEB); // node only
        k_zero_ds<<<(2 * N + 255) / 256, 256, 0, stream>>>(denom, 2 * N);
        int grid = (E + N + 255) / 256;
        k_edge_denom_dev<<<grid, 256, 0, stream>>>(ei, a_s, a_d, denom, E, N);
        k_edge_scatter_dev<<<grid, 256, 0, stream>>>(ei, a_s, a_d, denom, s_src, E, N);
    }

    k_colsum1<<<CSB, 512, 0, stream>>>(x, s_src, part, N);
    k_f3<<<1, 256, 0, stream>>>(part, W, bias, out, N, F_in, F_out);
}